// Round 1
// 420.058 us; speedup vs baseline: 1.0520x; 1.0520x over previous
//
#include <hip/hip_runtime.h>
#include <hip/hip_bf16.h>
#include <stdint.h>

#define B_   128
#define N_   196
#define E_   2048
#define D_   512
#define A_   512
#define MTOT (B_ * N_)   // 25088 = 392*64 exactly

typedef short  short8  __attribute__((ext_vector_type(8)));
typedef float  floatx4 __attribute__((ext_vector_type(4)));

__device__ __forceinline__ unsigned short f2bf(float f) {
    union { float f; uint32_t u; } v; v.f = f;
    uint32_t r = v.u + 0x7FFFu + ((v.u >> 16) & 1u);   // RNE
    return (unsigned short)(r >> 16);
}

// pack two fp32 -> two bf16 (round-half-up) in one dword: lo=bf16(a), hi=bf16(b)
__device__ __forceinline__ uint32_t pkbf(float a, float b) {
    uint32_t ua = __float_as_uint(a) + 0x8000u;
    uint32_t ub = __float_as_uint(b) + 0x8000u;
    return __builtin_amdgcn_perm(ub, ua, 0x07060302u);
}

// ---------------------------------------------------------------------------
// Kernel A2: We [2048][512] fp32 -> WeT [512][2048] bf16 (k-contiguous rows)
// ---------------------------------------------------------------------------
__global__ void transcvt_k(const float* __restrict__ We, unsigned short* __restrict__ WeT) {
    __shared__ float tile[32][33];
    const int e0 = blockIdx.x * 32, a0 = blockIdx.y * 32;
    const int t = threadIdx.x, tc = t & 31, tr = t >> 5;   // tr 0..7
#pragma unroll
    for (int i = 0; i < 4; ++i) {
        int r = tr + i * 8;
        tile[r][tc] = We[(size_t)(e0 + r) * A_ + a0 + tc];
    }
    __syncthreads();
#pragma unroll
    for (int i = 0; i < 4; ++i) {
        int r = tr + i * 8;
        WeT[(size_t)(a0 + r) * E_ + e0 + tc] = f2bf(tile[tc][r]);
    }
}

// ---------------------------------------------------------------------------
// Kernel A: att2p[b][a] = dh[b,:]@Wd[:,a] + bd[a] + be[a]   (fp32, tiny)
// ---------------------------------------------------------------------------
__launch_bounds__(512)
__global__ void att2_k(const float* __restrict__ dh, const float* __restrict__ Wd,
                       const float* __restrict__ bd, const float* __restrict__ be,
                       float* __restrict__ att2p) {
    const int b = blockIdx.x, t = threadIdx.x;
    __shared__ float sdh[D_];
    sdh[t] = dh[b * D_ + t];
    __syncthreads();
    float acc = 0.f;
#pragma unroll 8
    for (int d = 0; d < D_; ++d) acc += sdh[d] * Wd[(size_t)d * A_ + t];
    att2p[(size_t)b * A_ + t] = acc + bd[t] + be[t];
}

// ---------------------------------------------------------------------------
// Kernel B: fused bf16 MFMA GEMM (enc @ We) + tanh + dot(Wf) score epilogue.
// ONE block per 64-row strip covers ALL 512 columns -> enc read from HBM/L3
// exactly once; WeT (2 MB) streams from L2.
// 512 threads = 8 waves; wave w owns cols w*64..+63 (acc 4x4 = 64 regs).
//
// v2 (this round): 2-phase double-buffered pipeline (T3-minimum).
//   - per K-step: issue prefetch of tile k+1 (A->regs, B->LDS via
//     global_load_lds) BEFORE computing tile k; ONE barrier per iter.
//     Load latency hides under ds_read+MFMA instead of being 100% exposed.
//   - A stored in LDS as bf16 (converted once at staging): LDS traffic
//     96->64 KB/iter, inner-loop pkbf (16/wave/iter) eliminated, A-fragment
//     is a single ds_read_b128.
//   - LDS: buf = 4KB A(bf16 64x32) + 32KB B(bf16 512x32); x2 = 72 KB
//     -> still 2 blocks/CU.
//   - swizzle both A and B: 16B-chunk c' = c ^ ((row>>1)&3) -> 2-way (free)
//     bank pattern on fragment reads.
// ---------------------------------------------------------------------------
__launch_bounds__(512, 4)
__global__ void score_gemm(const float* __restrict__ enc,
                           const unsigned short* __restrict__ WeT,
                           const float* __restrict__ att2p,
                           const float* __restrict__ Wf,
                           float* __restrict__ scoresP) {
    __shared__ __align__(16) char sMem[2 * 36864];   // double buffer
    __shared__ float sPart[8][64];

    const int t   = threadIdx.x;
    const int w   = t >> 6;               // 0..7
    const int l   = t & 63;
    const int l15 = l & 15;
    const int q4  = l >> 4;
    const int row0 = blockIdx.x * 64;     // grid = 392

    floatx4 acc[4][4] = {};

    // ---- A staging (reg-staged fp32->bf16): thread t -> row r=t>>3, kseg p=t&7
    //      (kseg = 4 consecutive fp32 k-values = 8 bytes of bf16)
    const int ar = t >> 3, ap = t & 7;
    const float* aSrcT = enc + (size_t)(row0 + ar) * E_ + ap * 4;
    // byte offset inside A region: row*64, chunk c' = (ap>>1) ^ ((r>>1)&3), half ap&1
    const int aWr = ar * 64 + (((ap >> 1) ^ ((ar >> 1) & 3)) * 16) + (ap & 1) * 8;

    // ---- B DMA: 32 wave-insts (4/wave). slot s = (w*4+j)*64+l -> n=s>>2, p=s&3
    const unsigned short* bSrc[4];
    int bDst[4];
#pragma unroll
    for (int j = 0; j < 4; ++j) {
        int s = (w * 4 + j) * 64 + l;
        int n = s >> 2, p = s & 3;
        int q = p ^ ((n >> 1) & 3);
        bSrc[j] = WeT + (size_t)n * E_ + q * 8;
        bDst[j] = 4096 + (w * 4 + j) * 1024;   // B region starts at +4096
    }

    // ---- LDS read offsets (within one buffer)
    const int chA  = q4 ^ ((l15 >> 1) & 3);
    const int offA = l15 * 64 + chA * 16;                    // + mi*1024
    const int offB = 4096 + (w * 64 + l15) * 64 + chA * 16;  // + ni*1024

    // ---- prologue: stage tile 0 into buf0
    {
        float4 a0 = *(const float4*)(aSrcT);
#pragma unroll
        for (int j = 0; j < 4; ++j)
            __builtin_amdgcn_global_load_lds(
                (const __attribute__((address_space(1))) uint32_t*)(bSrc[j]),
                (__attribute__((address_space(3))) uint32_t*)(sMem + bDst[j]), 16, 0, 0);
        uint2 aw;
        aw.x = pkbf(a0.x, a0.y);
        aw.y = pkbf(a0.z, a0.w);
        *(uint2*)(sMem + aWr) = aw;            // compiler waits vmcnt for a0 only
        __syncthreads();                       // drains vmcnt(0)+lgkmcnt(0)
    }

    int cur = 0;
#pragma unroll 2
    for (int kk = 0; kk < 64; ++kk) {
        const int nxt = cur ^ 36864;
        const int kn  = (kk + 1) & 63;        // wrap at 63 -> harmless re-read of k=0

        // ---- prefetch next tile: A->regs first (enables counted vmcnt wait),
        //      then B->LDS[nxt] async
        float4 aNext = *(const float4*)(aSrcT + kn * 32);
#pragma unroll
        for (int j = 0; j < 4; ++j)
            __builtin_amdgcn_global_load_lds(
                (const __attribute__((address_space(1))) uint32_t*)(bSrc[j] + kn * 32),
                (__attribute__((address_space(3))) uint32_t*)(sMem + nxt + bDst[j]), 16, 0, 0);

        // ---- compute current tile
        short8 bfr[4];
#pragma unroll
        for (int ni = 0; ni < 4; ++ni)
            bfr[ni] = *(const short8*)(sMem + cur + offB + ni * 1024);
#pragma unroll
        for (int mi = 0; mi < 4; ++mi) {
            short8 a = *(const short8*)(sMem + cur + offA + mi * 1024);
            acc[mi][0] = __builtin_amdgcn_mfma_f32_16x16x32_bf16(a, bfr[0], acc[mi][0], 0, 0, 0);
            acc[mi][1] = __builtin_amdgcn_mfma_f32_16x16x32_bf16(a, bfr[1], acc[mi][1], 0, 0, 0);
            acc[mi][2] = __builtin_amdgcn_mfma_f32_16x16x32_bf16(a, bfr[2], acc[mi][2], 0, 0, 0);
            acc[mi][3] = __builtin_amdgcn_mfma_f32_16x16x32_bf16(a, bfr[3], acc[mi][3], 0, 0, 0);
        }

        // ---- write prefetched A into next buffer (vmcnt wait auto-inserted),
        //      then the single barrier: buf[nxt] fully ready on exit
        uint2 aw;
        aw.x = pkbf(aNext.x, aNext.y);
        aw.y = pkbf(aNext.z, aNext.w);
        *(uint2*)(sMem + nxt + aWr) = aw;
        __syncthreads();
        cur = nxt;
    }

    // Epilogue: s[m] = sum over ALL 512 cols of tanh(acc + att2p)*Wf -> complete score
    const int cbase = w * 64;
    float wfv[4];
#pragma unroll
    for (int ni = 0; ni < 4; ++ni) wfv[ni] = Wf[cbase + ni * 16 + l15];

#pragma unroll
    for (int mi = 0; mi < 4; ++mi) {
#pragma unroll
        for (int r = 0; r < 4; ++r) {
            const int m    = mi * 16 + q4 * 4 + r;     // D layout: row=(l>>4)*4+reg
            const int grow = row0 + m;
            const int bb   = grow / N_;
            const float* a2 = att2p + (size_t)bb * A_ + cbase;
            float s = 0.f;
#pragma unroll
            for (int ni = 0; ni < 4; ++ni) {
                float v  = acc[mi][ni][r] + a2[ni * 16 + l15];
                float e  = __expf(2.f * v);
                float th = 1.f - 2.f / (e + 1.f);      // tanh(v)
                s += th * wfv[ni];
            }
            s += __shfl_xor(s, 1);
            s += __shfl_xor(s, 2);
            s += __shfl_xor(s, 4);
            s += __shfl_xor(s, 8);
            if (l15 == 0) sPart[w][m] = s;
        }
    }
    __syncthreads();
    if (t < 64) {
        float v = 0.f;
#pragma unroll
        for (int ww = 0; ww < 8; ++ww) v += sPart[ww][t];
        scoresP[row0 + t] = v;
    }
}

// ---------------------------------------------------------------------------
// Kernel C0: softmax over N=196 per batch (bf bias dropped — softmax-invariant)
// ---------------------------------------------------------------------------
__global__ void softmax_k(const float* __restrict__ sp, float* __restrict__ alpha) {
    const int b = blockIdx.x, t = threadIdx.x;
    const int w = t >> 6, l = t & 63;
    __shared__ float red[8];
    float v = -3.0e38f;
    if (t < N_) v = sp[b * N_ + t];
    float m = v;
#pragma unroll
    for (int off = 32; off >= 1; off >>= 1) m = fmaxf(m, __shfl_xor(m, off));
    if (l == 0) red[w] = m;
    __syncthreads();
    m = fmaxf(fmaxf(red[0], red[1]), fmaxf(red[2], red[3]));
    float e = 0.f;
    if (t < N_) e = __expf(v - m);
    float s = e;
#pragma unroll
    for (int off = 32; off >= 1; off >>= 1) s += __shfl_xor(s, off);
    if (l == 0) red[4 + w] = s;
    __syncthreads();
    s = red[4] + red[5] + red[6] + red[7];
    if (t < N_) alpha[b * N_ + t] = e / s;
}

// ---------------------------------------------------------------------------
// Kernel C1: context[b, :] = sum_n alpha[b,n] * enc[b,n,:]   (fp32 stream)
// ---------------------------------------------------------------------------
__launch_bounds__(256)
__global__ void context_k(const float* __restrict__ enc, const float* __restrict__ alpha,
                          float* __restrict__ ctx) {
    const int chunk = blockIdx.x, b = blockIdx.y;
    const int t = threadIdx.x, tn = t >> 6, tc = t & 63;
    __shared__ float  sAl[N_];
    __shared__ float4 sRed[256];
    if (t < N_) sAl[t] = alpha[b * N_ + t];
    __syncthreads();
    const float* base = enc + (size_t)b * N_ * E_ + chunk * 256 + tc * 4;
    float4 a = make_float4(0.f, 0.f, 0.f, 0.f);
#pragma unroll 7
    for (int n = tn; n < N_; n += 4) {
        float  al = sAl[n];
        float4 v  = *(const float4*)(base + (size_t)n * E_);
        a.x += al * v.x; a.y += al * v.y; a.z += al * v.z; a.w += al * v.w;
    }
    sRed[t] = a;
    __syncthreads();
    if (t < 64) {
        float4 r0 = sRed[t], r1 = sRed[t + 64], r2 = sRed[t + 128], r3 = sRed[t + 192];
        float4 o = make_float4(r0.x + r1.x + r2.x + r3.x, r0.y + r1.y + r2.y + r3.y,
                               r0.z + r1.z + r2.z + r3.z, r0.w + r1.w + r2.w + r3.w);
        *(float4*)(ctx + (size_t)b * E_ + chunk * 256 + t * 4) = o;
    }
}

// ---------------------------------------------------------------------------
extern "C" void kernel_launch(void* const* d_in, const int* in_sizes, int n_in,
                              void* d_out, int out_size, void* d_ws, size_t ws_size,
                              hipStream_t stream) {
    const float* enc = (const float*)d_in[0];
    const float* dh  = (const float*)d_in[1];
    const float* We  = (const float*)d_in[2];
    const float* be  = (const float*)d_in[3];
    const float* Wd  = (const float*)d_in[4];
    const float* bd  = (const float*)d_in[5];
    const float* Wf  = (const float*)d_in[6];
    // d_in[7] = bf: additive constant on scores, cancels in softmax.

    float* out   = (float*)d_out;
    float* ctx   = out;              // [128, 2048]
    float* alpha = out + B_ * E_;    // [128, 196]

    char* ws = (char*)d_ws;
    unsigned short* WeT  = (unsigned short*)ws;                       // 2 MB
    float* att2p         = (float*)(ws + (2u << 20));                 // 256 KB
    float* scoresP       = (float*)(ws + (2u << 20) + (256u << 10));  // 25088 fp32

    transcvt_k <<<dim3(E_ / 32, A_ / 32), 256, 0, stream>>>(We, WeT);
    att2_k     <<<dim3(B_),              512, 0, stream>>>(dh, Wd, bd, be, att2p);
    score_gemm <<<dim3(MTOT / 64),       512, 0, stream>>>(enc, WeT, att2p, Wf, scoresP);
    softmax_k  <<<dim3(B_),              256, 0, stream>>>(scoresP, alpha);
    context_k  <<<dim3(E_ / 256, B_),    256, 0, stream>>>(enc, alpha, ctx);
}